// Round 3
// baseline (453.776 us; speedup 1.0000x reference)
//
#include <hip/hip_runtime.h>
#include <math.h>

// Problem constants
#define BB 32
#define DD 512
#define TT 64
#define RR 49
#define TR 3136      // TT*RR
#define KK 64
#define OUTN 1024
#define KD 32768     // KK*DD
#define PSTR 1048576ull  // vladP part stride in floats (BB*KK*DD)
#define NPH 6            // kB p-split phases (= vladP partial count)

typedef float f4 __attribute__((ext_vector_type(4)));
typedef short s8 __attribute__((ext_vector_type(8)));

// Workspace layout (byte offsets, all 256-aligned)
#define OFF_ASSIGN 0ull          // bf16 assign [32][64][3136]    = 12,845,056 B
#define OFF_VLADP  12845056ull   // fp32 vladP [6][32][64][512]   = 25,165,824 B
#define OFF_VN     38010880ull   // bf16 vlad_n [32][32768]       =  2,097,152 B
#define OFF_CWB    40108032ull   // bf16 conv_w [64][512]         =     65,536 B
#define OFF_SS     40173568ull   // fp32 ss [32][64]              =      8,192 B
#define OFF_ASUM   40181760ull   // fp32 asum [32][64]            =      8,192 B
#define OFF_Y      40189952ull   // fp32 y [32][1024]             =    131,072 B
// end: 40,321,024 B (~38.5 MB)

// Cheap fp32->bf16 pack: round-half-up (+0x8000 on bits) then v_perm high-half
// pack. 6 VALU ops per 4 elements vs ~20 for full RNE emulation.
__device__ __forceinline__ unsigned long long pack4(float a, float b, float c, float d) {
    union { float f; unsigned u; } A, B, C, D;
    A.f = a; B.f = b; C.f = c; D.f = d;
    unsigned lo = __builtin_amdgcn_perm(B.u + 0x8000u, A.u + 0x8000u, 0x07060302u);
    unsigned hi = __builtin_amdgcn_perm(D.u + 0x8000u, C.u + 0x8000u, 0x07060302u);
    return (unsigned long long)lo | ((unsigned long long)hi << 32);
}

// ---------------------------------------------------------------------------
// kW: one-time conv_w fp32 -> bf16 convert (shared by all 1568 kA blocks)
// ---------------------------------------------------------------------------
__global__ __launch_bounds__(256) void kW(const float* __restrict__ convw,
                                          unsigned short* __restrict__ cwb) {
    int idx = blockIdx.x * 256 + threadIdx.x;   // 8192 f4's total
    f4 v = *(const f4*)(convw + idx * 4);
    *(unsigned long long*)(cwb + idx * 4) = pack4(v[0], v[1], v[2], v[3]);
}

// ---------------------------------------------------------------------------
// kA: logits = conv_w @ x (MFMA bf16), softmax over k, mask, asum, assign(bf16)
// grid 32*49, block 256. Per block: 64 k x 64 p, K-loop over d=512.
// v4: double-buffered LDS + 1-deep load-ahead in NAMED f4 regs (round-1's
// array version spilled to scratch via runtime vector indexing, rule #20 —
// named scalars are SROA-safe; the runtime j extract is the round-0-proven
// cndmask pattern). One barrier per K-step. sm aliased onto xT0.
// ---------------------------------------------------------------------------
__global__ __launch_bounds__(256) void kA(const float* __restrict__ x,
                                          const int* __restrict__ mask,
                                          const unsigned short* __restrict__ cwb,
                                          unsigned short* __restrict__ assign,
                                          float* __restrict__ asum) {
    __shared__ unsigned short xT0[64 * 136];   // [p][d-chunk 128 + pad]
    __shared__ unsigned short xT1[64 * 136];
    __shared__ float redM[256], redS[256];     // softmax reduce buffers
    float* sm = (float*)xT0;                   // [k][p] logits; alias, phase 2

    const int blk = blockIdx.x;
    const int b = blk / 49;
    const int pc = blk % 49;
    const int p0 = pc * 64;
    const int tid = threadIdx.x;
    const int lane = tid & 63;
    const int wv = tid >> 6;
    const int quad = lane >> 4;
    const int l15 = lane & 15;
    const int pq = tid & 15;
    const int dq0 = tid >> 4;   // 0..15

    f4 acc[4];
#pragma unroll
    for (int t = 0; t < 4; ++t) acc[t] = (f4){0.f, 0.f, 0.f, 0.f};

    const float* xb = x + (size_t)b * DD * TR + p0 + pq * 4;
    const unsigned short* cwrow = cwb + (wv * 16 + l15) * DD + quad * 8;

    // 1-chunk-ahead pipeline regs: NAMED scalars (no arrays -> no alloca).
    f4 g00, g01, g02, g03;   // d-rows dq0*4 .. +3
    f4 g10, g11, g12, g13;   // d-rows (dq0+16)*4 .. +3

#define KA_XLOAD(D0)                                                          \
    {                                                                         \
        const float* xp0 = xb + (size_t)((D0) + dq0 * 4) * TR;                \
        const float* xp1 = xb + (size_t)((D0) + (dq0 + 16) * 4) * TR;         \
        g00 = *(const f4*)(xp0);          g01 = *(const f4*)(xp0 + TR);       \
        g02 = *(const f4*)(xp0 + 2 * TR); g03 = *(const f4*)(xp0 + 3 * TR);   \
        g10 = *(const f4*)(xp1);          g11 = *(const f4*)(xp1 + TR);       \
        g12 = *(const f4*)(xp1 + 2 * TR); g13 = *(const f4*)(xp1 + 3 * TR);   \
    }

#define KA_XST1(BUF, JJ)                                                      \
    {                                                                         \
        int j = ((JJ) + pq) & 3; /* stagger spreads LDS banks */              \
        *(unsigned long long*)((BUF) + (pq * 4 + j) * 136 + dq0 * 4) =        \
            pack4(g00[j], g01[j], g02[j], g03[j]);                            \
        *(unsigned long long*)((BUF) + (pq * 4 + j) * 136 + (dq0 + 16) * 4) = \
            pack4(g10[j], g11[j], g12[j], g13[j]);                            \
    }
#define KA_XSTORE(BUF) { KA_XST1(BUF, 0) KA_XST1(BUF, 1) KA_XST1(BUF, 2) KA_XST1(BUF, 3) }

    // prologue: stage chunk 0, prefetch chunk 1 into regs
    KA_XLOAD(0);
    KA_XSTORE(xT0);
    KA_XLOAD(128);
    __syncthreads();

#pragma unroll
    for (int dc = 0; dc < 4; ++dc) {
        unsigned short* cur = (dc & 1) ? xT1 : xT0;
        unsigned short* nxt = (dc & 1) ? xT0 : xT1;
        if (dc < 3) KA_XSTORE(nxt);            // regs hold chunk dc+1
        if (dc < 2) KA_XLOAD((dc + 2) * 128);  // refill regs with chunk dc+2
        s8 af[4];
        af[0] = *(const s8*)(cwrow + dc * 128);
        af[1] = *(const s8*)(cwrow + dc * 128 + 32);
        af[2] = *(const s8*)(cwrow + dc * 128 + 64);
        af[3] = *(const s8*)(cwrow + dc * 128 + 96);
#pragma unroll
        for (int ks = 0; ks < 4; ++ks) {
            int off = ks * 32 + quad * 8;
#pragma unroll
            for (int t = 0; t < 4; ++t) {
                s8 bfr = *(const s8*)(cur + (t * 16 + l15) * 136 + off);
                acc[t] = __builtin_amdgcn_mfma_f32_16x16x32_bf16(af[ks], bfr, acc[t], 0, 0, 0);
            }
        }
        __syncthreads();   // one barrier per K-step
    }

    // dump C/D frags to sm[k][p] (sm aliases xT0; all MFMA reads are behind
    // the loop's final barrier): col=lane&15 (p), row=quad*4+reg (k)
#pragma unroll
    for (int t = 0; t < 4; ++t)
#pragma unroll
        for (int r = 0; r < 4; ++r)
            sm[(wv * 16 + quad * 4 + r) * 68 + t * 16 + l15] = acc[t][r];
    __syncthreads();

    // parallel softmax over k per column p: wave wv owns k in [wv*16, wv*16+16)
    const int p = lane;
    float mx = -1e30f;
#pragma unroll
    for (int i = 0; i < 16; ++i) mx = fmaxf(mx, sm[(wv * 16 + i) * 68 + p]);
    redM[wv * 64 + p] = mx;
    __syncthreads();
    mx = fmaxf(fmaxf(redM[p], redM[64 + p]), fmaxf(redM[128 + p], redM[192 + p]));
    float s = 0.f;
#pragma unroll
    for (int i = 0; i < 16; ++i) {
        float e = __expf(sm[(wv * 16 + i) * 68 + p] - mx);
        sm[(wv * 16 + i) * 68 + p] = e;
        s += e;
    }
    redS[wv * 64 + p] = s;
    __syncthreads();
    float tot = redS[p] + redS[64 + p] + redS[128 + p] + redS[192 + p];
    const int tt = (p0 + p) / RR;
    const float inv = (float)mask[b * TT + tt] / tot;
    // scale + per-k wave-reduced asum
#pragma unroll
    for (int i = 0; i < 16; ++i) {
        float v = sm[(wv * 16 + i) * 68 + p] * inv;
        sm[(wv * 16 + i) * 68 + p] = v;
        float r = v;
#pragma unroll
        for (int off = 32; off > 0; off >>= 1) r += __shfl_down(r, off, 64);
        if (lane == 0) atomicAdd(&asum[b * 64 + wv * 16 + i], r);
    }
    __syncthreads();
    // write assign bf16 [k][p]
#pragma unroll
    for (int i = 0; i < 4; ++i) {
        int lin = i * 256 + tid;
        int kr = lin >> 4;
        int pqq = lin & 15;
        f4 v = *(const f4*)(sm + kr * 68 + pqq * 4);
        *(unsigned long long*)(assign + (size_t)(b * 64 + kr) * TR + p0 + pqq * 4) =
            pack4(v[0], v[1], v[2], v[3]);
    }
}

// ---------------------------------------------------------------------------
// kB: vladP[ph][b,k,d] = sum_{p in sixth} assign[k][p]*x[d][p]  (MFMA bf16)
// part 0 additionally subtracts asum*centroid. grid 32*8*6 = 1536 (was 1024,
// grid-limited at 4 blk/CU; 6 blk/CU now), block 256, launch_bounds(256,6).
// Load-ahead pipeline (static-indexed regs — safe from scratch demotion).
// ---------------------------------------------------------------------------
__global__ __launch_bounds__(256, 6) void kB(const float* __restrict__ x,
                                             const unsigned short* __restrict__ assign,
                                             const float* __restrict__ asum,
                                             const float* __restrict__ cent,
                                             float* __restrict__ vladP) {
    __shared__ unsigned short as_l[64 * 72];  // [k][p-chunk 64 + pad]
    __shared__ unsigned short x_l[64 * 72];   // [d][p-chunk 64 + pad]

    const int blk = blockIdx.x;
    const int b   = blk / 48;
    const int rem = blk % 48;
    const int ds  = rem / NPH;
    const int ph  = rem % NPH;
    const int d0 = ds * 64;
    const int tid = threadIdx.x;
    const int lane = tid & 63;
    const int wv = tid >> 6;
    const int quad = lane >> 4;
    const int l15 = lane & 15;

    f4 acc[4];
#pragma unroll
    for (int t = 0; t < 4; ++t) acc[t] = (f4){0.f, 0.f, 0.f, 0.f};

    const int pcs = (ph * 49) / NPH;         // 0,8,16,24,32,40
    const int pce = ((ph + 1) * 49) / NPH;   // 8,16,24,32,40,49

    const int ar0 = tid >> 3, ac0 = tid & 7;   // assign staging
    const int xr0 = tid >> 4, xc0 = tid & 15;  // x staging

    s8 asr[2];
    f4 xrr[4];
    auto LOADB = [&](int pc) {
        const int pp = pc * 64;
#pragma unroll
        for (int i = 0; i < 2; ++i)
            asr[i] = *(const s8*)(assign + (size_t)(b * 64 + ar0 + i * 32) * TR + pp + ac0 * 8);
#pragma unroll
        for (int i = 0; i < 4; ++i)
            xrr[i] = *(const f4*)(x + (size_t)(b * DD + d0 + xr0 + i * 16) * TR + pp + xc0 * 4);
    };
    auto STOREB = [&]() {
#pragma unroll
        for (int i = 0; i < 2; ++i)
            *(s8*)(as_l + (ar0 + i * 32) * 72 + ac0 * 8) = asr[i];
#pragma unroll
        for (int i = 0; i < 4; ++i)
            *(unsigned long long*)(x_l + (xr0 + i * 16) * 72 + xc0 * 4) =
                pack4(xrr[i][0], xrr[i][1], xrr[i][2], xrr[i][3]);
    };

    LOADB(pcs);
    for (int pc = pcs; pc < pce; ++pc) {
        __syncthreads();
        STOREB();
        if (pc + 1 < pce) LOADB(pc + 1);   // next-tile loads fly over MFMA phase
        __syncthreads();
#pragma unroll
        for (int ks = 0; ks < 2; ++ks) {
            const int off = ks * 32 + quad * 8;
            s8 af = *(const s8*)(as_l + (wv * 16 + l15) * 72 + off);
#pragma unroll
            for (int t = 0; t < 4; ++t) {
                s8 bfr = *(const s8*)(x_l + (t * 16 + l15) * 72 + off);
                acc[t] = __builtin_amdgcn_mfma_f32_16x16x32_bf16(af, bfr, acc[t], 0, 0, 0);
            }
        }
    }
    float* vp = vladP + (size_t)ph * PSTR;
#pragma unroll
    for (int r = 0; r < 4; ++r) {
        const int k = wv * 16 + quad * 4 + r;
        float corr = (ph == 0) ? asum[b * 64 + k] : 0.f;
#pragma unroll
        for (int t = 0; t < 4; ++t) {
            const int d = d0 + t * 16 + l15;
            float v = acc[t][r];
            if (ph == 0) v -= corr * cent[k * DD + d];
            vp[(size_t)(b * 64 + k) * DD + d] = v;
        }
    }
}

// ---------------------------------------------------------------------------
// kC1: per-row sum of squares of sum of 6 partials. grid 32*8, block 256.
// ---------------------------------------------------------------------------
__global__ __launch_bounds__(256) void kC1(const float* __restrict__ vladP,
                                           float* __restrict__ ss) {
    const int blk = blockIdx.x;
    const int b = blk >> 3;
    const int ks = blk & 7;
    const int tid = threadIdx.x;
    const int kr = tid >> 5;
    const int l32 = tid & 31;
    const int k = ks * 8 + kr;
    const float* q = vladP + (size_t)(b * 64 + k) * DD;
    float s = 0.f;
#pragma unroll
    for (int i = 0; i < 4; ++i) {
        f4 v = *(const f4*)(q + i * 128 + l32 * 4);
#pragma unroll
        for (int pp = 1; pp < NPH; ++pp) {
            f4 a = *(const f4*)(q + pp * PSTR + i * 128 + l32 * 4);
            v[0] += a[0]; v[1] += a[1]; v[2] += a[2]; v[3] += a[3];
        }
#pragma unroll
        for (int j = 0; j < 4; ++j) s = fmaf(v[j], v[j], s);
    }
    for (int off = 16; off > 0; off >>= 1) s += __shfl_down(s, off, 32);
    if (l32 == 0) ss[b * 64 + k] = s;
}

// ---------------------------------------------------------------------------
// kC2: scales = intra*global norm; write vlad_n bf16. grid 32*8, block 256.
// ---------------------------------------------------------------------------
__global__ __launch_bounds__(256) void kC2(const float* __restrict__ vladP,
                                           const float* __restrict__ ss,
                                           unsigned short* __restrict__ vn) {
    __shared__ float sc[64];
    const int blk = blockIdx.x;
    const int b = blk >> 3;
    const int js = blk & 7;
    const int tid = threadIdx.x;
    if (tid < 64) {
        float rn = sqrtf(ss[b * 64 + tid]);
        float inv = 1.f / fmaxf(rn, 1e-12f);
        float cb = rn * inv; cb = cb * cb;
        float g = cb;
        for (int off = 32; off > 0; off >>= 1) g += __shfl_down(g, off, 64);
        g = __shfl(g, 0, 64);
        float gi = 1.f / fmaxf(sqrtf(g), 1e-12f);
        sc[tid] = inv * gi;
    }
    __syncthreads();
    const float* q = vladP + (size_t)b * KD;
#pragma unroll
    for (int it = 0; it < 4; ++it) {
        int j = js * 4096 + it * 1024 + tid * 4;
        f4 v = *(const f4*)(q + j);
#pragma unroll
        for (int pp = 1; pp < NPH; ++pp) {
            f4 a = *(const f4*)(q + pp * PSTR + j);
            v[0] += a[0]; v[1] += a[1]; v[2] += a[2]; v[3] += a[3];
        }
        float scl = sc[j >> 9];
        *(unsigned long long*)(vn + (size_t)b * KD + j) =
            pack4(v[0] * scl, v[1] * scl, v[2] * scl, v[3] * scl);
    }
}

// ---------------------------------------------------------------------------
// kD: y[b,o] += vlad_n @ red_w^T (MFMA bf16). grid 16 o-tiles * 64 j-splits
// (was 32: 2 blk/CU -> 4 blk/CU), block 256. Static-indexed load-ahead.
// ---------------------------------------------------------------------------
__global__ __launch_bounds__(256) void kD(const unsigned short* __restrict__ vn,
                                          const float* __restrict__ redw,
                                          float* __restrict__ y) {
    __shared__ unsigned short rw_l[64 * 136];  // [o][j-chunk 128 + pad]
    __shared__ unsigned short vl_l[32 * 136];  // [b][j-chunk 128 + pad]

    const int blk = blockIdx.x;
    const int ot = blk & 15;
    const int js = blk >> 4;      // 0..63
    const int o0 = ot * 64;
    const int jb = js * 512;
    const int tid = threadIdx.x;
    const int lane = tid & 63;
    const int wv = tid >> 6;
    const int quad = lane >> 4;
    const int l15 = lane & 15;

    f4 acc[2];
    acc[0] = (f4){0.f, 0.f, 0.f, 0.f};
    acc[1] = (f4){0.f, 0.f, 0.f, 0.f};

    const int rr0 = tid >> 5, rc0 = tid & 31;  // redw staging
    const int vr0 = tid >> 4, vc0 = tid & 15;  // vn staging
    f4 rwr[8];
    s8 vlr[2];
    auto LOADD = [&](int jc) {
        const int j0 = jb + jc * 128;
#pragma unroll
        for (int i = 0; i < 8; ++i)
            rwr[i] = *(const f4*)(redw + (size_t)(o0 + rr0 + i * 8) * KD + j0 + rc0 * 4);
#pragma unroll
        for (int i = 0; i < 2; ++i)
            vlr[i] = *(const s8*)(vn + (size_t)(vr0 + i * 16) * KD + j0 + vc0 * 8);
    };
    auto STORED = [&]() {
#pragma unroll
        for (int i = 0; i < 8; ++i)
            *(unsigned long long*)(rw_l + (rr0 + i * 8) * 136 + rc0 * 4) =
                pack4(rwr[i][0], rwr[i][1], rwr[i][2], rwr[i][3]);
#pragma unroll
        for (int i = 0; i < 2; ++i)
            *(s8*)(vl_l + (vr0 + i * 16) * 136 + vc0 * 8) = vlr[i];
    };

    LOADD(0);
    for (int jc = 0; jc < 4; ++jc) {
        __syncthreads();
        STORED();
        if (jc < 3) LOADD(jc + 1);
        __syncthreads();
#pragma unroll
        for (int ks = 0; ks < 4; ++ks) {
            const int off = ks * 32 + quad * 8;
            s8 bfr = *(const s8*)(rw_l + (wv * 16 + l15) * 136 + off);
#pragma unroll
            for (int t = 0; t < 2; ++t) {
                s8 af = *(const s8*)(vl_l + (t * 16 + l15) * 136 + off);
                acc[t] = __builtin_amdgcn_mfma_f32_16x16x32_bf16(af, bfr, acc[t], 0, 0, 0);
            }
        }
    }
#pragma unroll
    for (int t = 0; t < 2; ++t)
#pragma unroll
        for (int r = 0; r < 4; ++r) {
            int bq = t * 16 + quad * 4 + r;
            int o = o0 + wv * 16 + l15;
            atomicAdd(&y[(size_t)bq * OUTN + o], acc[t][r]);
        }
}

// ---------------------------------------------------------------------------
// kE: LayerNorm over OUT per b -> d_out. grid 32, block 256.
// ---------------------------------------------------------------------------
__global__ __launch_bounds__(256) void kE(const float* __restrict__ y,
                                          const float* __restrict__ gamma,
                                          const float* __restrict__ beta,
                                          float* __restrict__ out) {
    __shared__ float s1s[4], s2s[4];
    __shared__ float mu_s, rstd_s;

    const int b = blockIdx.x;
    const int tid = threadIdx.x;
    const int wave = tid >> 6;
    const int lane = tid & 63;

    f4 v = *(const f4*)(y + (size_t)b * OUTN + tid * 4);
    float s1 = v[0] + v[1] + v[2] + v[3];
    float s2 = v[0] * v[0] + v[1] * v[1] + v[2] * v[2] + v[3] * v[3];
    for (int off = 32; off > 0; off >>= 1) {
        s1 += __shfl_down(s1, off, 64);
        s2 += __shfl_down(s2, off, 64);
    }
    if (lane == 0) { s1s[wave] = s1; s2s[wave] = s2; }
    __syncthreads();
    if (tid == 0) {
        float S1 = s1s[0] + s1s[1] + s1s[2] + s1s[3];
        float S2 = s2s[0] + s2s[1] + s2s[2] + s2s[3];
        float mu = S1 / (float)OUTN;
        float var = S2 / (float)OUTN - mu * mu;
        mu_s = mu;
        rstd_s = 1.0f / sqrtf(var + 1e-5f);
    }
    __syncthreads();
    const float mu = mu_s, rstd = rstd_s;
    f4 g = *(const f4*)(gamma + tid * 4);
    f4 be = *(const f4*)(beta + tid * 4);
    f4 o;
#pragma unroll
    for (int i = 0; i < 4; ++i) o[i] = (v[i] - mu) * rstd * g[i] + be[i];
    *(f4*)(out + (size_t)b * OUTN + tid * 4) = o;
}

// ---------------------------------------------------------------------------
extern "C" void kernel_launch(void* const* d_in, const int* in_sizes, int n_in,
                              void* d_out, int out_size, void* d_ws, size_t ws_size,
                              hipStream_t stream) {
    const float* x     = (const float*)d_in[0];
    const int*   mask  = (const int*)d_in[1];
    const float* cent  = (const float*)d_in[2];
    const float* convw = (const float*)d_in[3];
    const float* redw  = (const float*)d_in[4];
    const float* gam   = (const float*)d_in[5];
    const float* bet   = (const float*)d_in[6];
    float* out = (float*)d_out;
    char* w = (char*)d_ws;

    unsigned short* assign = (unsigned short*)(w + OFF_ASSIGN);
    float*          vladP  = (float*)(w + OFF_VLADP);
    unsigned short* vn     = (unsigned short*)(w + OFF_VN);
    unsigned short* cwb    = (unsigned short*)(w + OFF_CWB);
    float*          ss     = (float*)(w + OFF_SS);
    float*          asum   = (float*)(w + OFF_ASUM);
    float*          y      = (float*)(w + OFF_Y);

    hipMemsetAsync(asum, 0, 64 * BB * sizeof(float), stream);
    hipMemsetAsync(y, 0, BB * OUTN * sizeof(float), stream);

    kW<<<32, 256, 0, stream>>>(convw, cwb);
    kA<<<BB * 49, 256, 0, stream>>>(x, mask, cwb, assign, asum);
    kB<<<BB * 8 * NPH, 256, 0, stream>>>(x, assign, asum, cent, vladP);
    kC1<<<BB * 8, 256, 0, stream>>>(vladP, ss);
    kC2<<<BB * 8, 256, 0, stream>>>(vladP, ss, vn);
    kD<<<16 * 64, 256, 0, stream>>>(vn, redw, y);
    kE<<<BB, 256, 0, stream>>>(y, gam, bet, out);
}